// Round 1
// baseline (438.922 us; speedup 1.0000x reference)
//
#include <hip/hip_runtime.h>

typedef unsigned short u16;
typedef unsigned int u32;

#define E_EDGES 600000
#define NUM_FINE 50000
#define NUM_COARSE 12500

typedef __attribute__((ext_vector_type(8))) short short8;
typedef __attribute__((ext_vector_type(4))) float f32x4;

union Frag { short8 v; u16 s[8]; u32 u[4]; uint4 q; };

__device__ __forceinline__ u32 rne_bf16(float f) {
  union { float f; u32 u; } v; v.f = f;
  return (v.u + 0x7FFFu + ((v.u >> 16) & 1u)) >> 16;
}
__device__ __forceinline__ float bf2f(u32 bits16) {
  union { u32 u; float f; } v; v.u = bits16 << 16; return v.f;
}
// add two bf16 pairs in f32, relu, repack to bf16 pair
__device__ __forceinline__ u32 addrelu_pack(u32 a, u32 b) {
  float lo = fmaxf(bf2f(a & 0xFFFFu) + bf2f(b & 0xFFFFu), 0.0f);
  float hi = fmaxf(bf2f(a >> 16) + bf2f(b >> 16), 0.0f);
  return rne_bf16(lo) | (rne_bf16(hi) << 16);
}

// ---------------------------------------------------------------------------
// Kernel 1: P_fine  = h_si_fine @ W1[0:128]   + h_di_fine @ W1[256:384]
//           P_coarse= h_sk_coarse @ W1[128:256] + h_dk_coarse @ W1[384:512] + b1
// Output stored as bf16 [rows,128]. 128 rows / block, 256 threads (4 waves).
// B (W-slices, K=256 x N=128) staged in LDS in MFMA B-fragment order.
// A fragments loaded f32 from global directly into registers.
// ---------------------------------------------------------------------------
#define FINE_BLOCKS 391   // ceil(50000/128)
#define COARSE_BLOCKS 98  // ceil(12500/128)

__global__ __launch_bounds__(256, 2) void precompute_kernel(
    const float* __restrict__ h_dk_coarse, const float* __restrict__ h_si_fine,
    const float* __restrict__ h_sk_coarse, const float* __restrict__ h_di_fine,
    const float* __restrict__ W1, const float* __restrict__ b1,
    u16* __restrict__ Pf, u16* __restrict__ Pc) {
  __shared__ u16 Bfrag[8 * 8 * 64 * 8];  // [ks][nt][lane][j], 64 KB

  const int b = blockIdx.x;
  const bool fine = b < FINE_BLOCKS;
  const int rowStart = fine ? b * 128 : (b - FINE_BLOCKS) * 128;
  const int R = fine ? NUM_FINE : NUM_COARSE;
  const float* __restrict__ X1 = fine ? h_si_fine : h_sk_coarse;
  const float* __restrict__ X2 = fine ? h_di_fine : h_dk_coarse;
  const int wbase1 = fine ? 0 : 128;
  const int wbase2 = fine ? 256 : 384;
  u16* __restrict__ P = fine ? Pf : Pc;

  const int tid = threadIdx.x;

  // Stage W slice (256 x 128) into fragment-ordered LDS as bf16.
  for (int p = 0; p < 2; ++p) {
    const int kl = p * 128 + (tid >> 1);      // 0..255
    const int nh = (tid & 1) * 64;
    const int wrow = (kl < 128) ? (wbase1 + kl) : (wbase2 + (kl - 128));
    const float4* __restrict__ src = (const float4*)(W1 + wrow * 128 + nh);
    const int ks = kl >> 5, qd = (kl >> 3) & 3, j = kl & 7;
#pragma unroll 4
    for (int g4 = 0; g4 < 16; ++g4) {
      float4 v = src[g4];
      const int n = nh + g4 * 4;          // n%4==0, all 4 in same nt
      const int nt = n >> 4;
      u16* dst = &Bfrag[(((ks * 8 + nt) * 64) + qd * 16 + (n & 15)) * 8 + j];
      dst[0]  = (u16)rne_bf16(v.x);
      dst[8]  = (u16)rne_bf16(v.y);
      dst[16] = (u16)rne_bf16(v.z);
      dst[24] = (u16)rne_bf16(v.w);
    }
  }
  __syncthreads();

  const int lane = tid & 63;
  const int w = tid >> 6;
  const int qd = lane >> 4;
  const int ml = lane & 15;

  int rowA[2];
  bool vA[2];
#pragma unroll
  for (int mt = 0; mt < 2; ++mt) {
    rowA[mt] = rowStart + w * 32 + mt * 16 + ml;
    vA[mt] = rowA[mt] < R;
  }

  f32x4 acc[2][8];
#pragma unroll
  for (int mt = 0; mt < 2; ++mt)
#pragma unroll
    for (int nt = 0; nt < 8; ++nt) acc[mt][nt] = (f32x4){0.f, 0.f, 0.f, 0.f};

  for (int ks = 0; ks < 8; ++ks) {
    const int k0 = ks * 32 + qd * 8;  // 0..255, 8 contiguous k per lane
    short8 a[2];
#pragma unroll
    for (int mt = 0; mt < 2; ++mt) {
      Frag af;
      if (vA[mt]) {
        const float* src = (k0 < 128) ? (X1 + rowA[mt] * 128 + k0)
                                      : (X2 + rowA[mt] * 128 + (k0 - 128));
        const float4* s4 = (const float4*)src;
        float4 v0 = s4[0], v1 = s4[1];
        af.u[0] = rne_bf16(v0.x) | (rne_bf16(v0.y) << 16);
        af.u[1] = rne_bf16(v0.z) | (rne_bf16(v0.w) << 16);
        af.u[2] = rne_bf16(v1.x) | (rne_bf16(v1.y) << 16);
        af.u[3] = rne_bf16(v1.z) | (rne_bf16(v1.w) << 16);
      } else {
        af.u[0] = af.u[1] = af.u[2] = af.u[3] = 0u;
      }
      a[mt] = af.v;
    }
#pragma unroll
    for (int nt = 0; nt < 8; ++nt) {
      Frag bfr;
      bfr.q = *(const uint4*)&Bfrag[((ks * 8 + nt) * 64 + lane) * 8];
      acc[0][nt] = __builtin_amdgcn_mfma_f32_16x16x32_bf16(a[0], bfr.v, acc[0][nt], 0, 0, 0);
      acc[1][nt] = __builtin_amdgcn_mfma_f32_16x16x32_bf16(a[1], bfr.v, acc[1][nt], 0, 0, 0);
    }
  }

  // Epilogue: (+b1 for coarse), bf16 store. D: row = qd*4+r, col = nt*16+ml.
  float b1v[8];
#pragma unroll
  for (int nt = 0; nt < 8; ++nt) b1v[nt] = fine ? 0.0f : b1[nt * 16 + ml];

#pragma unroll
  for (int mt = 0; mt < 2; ++mt) {
#pragma unroll
    for (int r = 0; r < 4; ++r) {
      const int row = rowStart + w * 32 + mt * 16 + qd * 4 + r;
      if (row < R) {
#pragma unroll
        for (int nt = 0; nt < 8; ++nt) {
          const int col = nt * 16 + ml;
          P[row * 128 + col] = (u16)rne_bf16(acc[mt][nt][r] + b1v[nt]);
        }
      }
    }
  }
}

// ---------------------------------------------------------------------------
// Kernel 2: per 128-edge tile:
//   h   = relu(Pf[fine_idx] + Pc[coarse_idx])            (bf16 A-fragments)
//   psi = relu(h @ W2 + b2)                              (MFMA, W2 in LDS)
//   atomicAdd(out[fine_idx], psi * h_dk_coarse[coarse_idx])
// ---------------------------------------------------------------------------
__global__ __launch_bounds__(256, 4) void edge_kernel(
    const u16* __restrict__ Pf, const u16* __restrict__ Pc,
    const float* __restrict__ h_dk_coarse,
    const int* __restrict__ fine_idx, const int* __restrict__ coarse_idx,
    const float* __restrict__ W2, const float* __restrict__ b2,
    float* __restrict__ out) {
  __shared__ u16 Bfrag[4 * 8 * 64 * 8];  // W2 fragments, 32 KB

  const int tid = threadIdx.x;
  {  // stage W2 (128x128) into fragment-ordered LDS
    const int kl = tid >> 1;
    const int nh = (tid & 1) * 64;
    const float4* __restrict__ src = (const float4*)(W2 + kl * 128 + nh);
    const int ks = kl >> 5, qd = (kl >> 3) & 3, j = kl & 7;
#pragma unroll 4
    for (int g4 = 0; g4 < 16; ++g4) {
      float4 v = src[g4];
      const int n = nh + g4 * 4;
      const int nt = n >> 4;
      u16* dst = &Bfrag[(((ks * 8 + nt) * 64) + qd * 16 + (n & 15)) * 8 + j];
      dst[0]  = (u16)rne_bf16(v.x);
      dst[8]  = (u16)rne_bf16(v.y);
      dst[16] = (u16)rne_bf16(v.z);
      dst[24] = (u16)rne_bf16(v.w);
    }
  }
  __syncthreads();

  const int lane = tid & 63;
  const int w = tid >> 6;
  const int qd = lane >> 4;
  const int ml = lane & 15;
  const int ebase = blockIdx.x * 128;

  int fiA[2], ciA[2];
  bool vA[2];
#pragma unroll
  for (int mt = 0; mt < 2; ++mt) {
    const int e = ebase + w * 32 + mt * 16 + ml;
    vA[mt] = e < E_EDGES;
    fiA[mt] = vA[mt] ? fine_idx[e] : 0;
    ciA[mt] = vA[mt] ? coarse_idx[e] : 0;
  }

  f32x4 acc[2][8];
#pragma unroll
  for (int mt = 0; mt < 2; ++mt)
#pragma unroll
    for (int nt = 0; nt < 8; ++nt) acc[mt][nt] = (f32x4){0.f, 0.f, 0.f, 0.f};

  for (int ks = 0; ks < 4; ++ks) {
    const int k0 = ks * 32 + qd * 8;
    short8 a[2];
#pragma unroll
    for (int mt = 0; mt < 2; ++mt) {
      Frag af;
      if (vA[mt]) {
        uint4 pf = *(const uint4*)(Pf + fiA[mt] * 128 + k0);
        uint4 pc = *(const uint4*)(Pc + ciA[mt] * 128 + k0);
        af.u[0] = addrelu_pack(pf.x, pc.x);
        af.u[1] = addrelu_pack(pf.y, pc.y);
        af.u[2] = addrelu_pack(pf.z, pc.z);
        af.u[3] = addrelu_pack(pf.w, pc.w);
      } else {
        af.u[0] = af.u[1] = af.u[2] = af.u[3] = 0u;
      }
      a[mt] = af.v;
    }
#pragma unroll
    for (int nt = 0; nt < 8; ++nt) {
      Frag bfr;
      bfr.q = *(const uint4*)&Bfrag[((ks * 8 + nt) * 64 + lane) * 8];
      acc[0][nt] = __builtin_amdgcn_mfma_f32_16x16x32_bf16(a[0], bfr.v, acc[0][nt], 0, 0, 0);
      acc[1][nt] = __builtin_amdgcn_mfma_f32_16x16x32_bf16(a[1], bfr.v, acc[1][nt], 0, 0, 0);
    }
  }

  // Epilogue: psi = relu(acc + b2), contrib = psi * h_dk_g, atomic scatter.
  float b2v[8];
#pragma unroll
  for (int nt = 0; nt < 8; ++nt) b2v[nt] = b2[nt * 16 + ml];

#pragma unroll
  for (int mt = 0; mt < 2; ++mt) {
#pragma unroll
    for (int r = 0; r < 4; ++r) {
      const int e = ebase + w * 32 + mt * 16 + qd * 4 + r;
      if (e < E_EDGES) {
        const int fi = fine_idx[e];
        const int ci = coarse_idx[e];
        const float* __restrict__ hdk = h_dk_coarse + ci * 128;
        float* __restrict__ op = out + fi * 128;
#pragma unroll
        for (int nt = 0; nt < 8; ++nt) {
          const int col = nt * 16 + ml;
          const float psi = fmaxf(acc[mt][nt][r] + b2v[nt], 0.0f);
          atomicAdd(op + col, psi * hdk[col]);
        }
      }
    }
  }
}

extern "C" void kernel_launch(void* const* d_in, const int* in_sizes, int n_in,
                              void* d_out, int out_size, void* d_ws, size_t ws_size,
                              hipStream_t stream) {
  const float* h_dk = (const float*)d_in[0];
  const float* h_si = (const float*)d_in[1];
  const float* h_sk = (const float*)d_in[2];
  const float* h_di = (const float*)d_in[3];
  const int* fidx = (const int*)d_in[4];
  const int* cidx = (const int*)d_in[5];
  const float* W1 = (const float*)d_in[6];
  const float* b1 = (const float*)d_in[7];
  const float* W2 = (const float*)d_in[8];
  const float* b2 = (const float*)d_in[9];
  float* out = (float*)d_out;

  u16* Pf = (u16*)d_ws;                      // [NUM_FINE][128] bf16, 12.8 MB
  u16* Pc = Pf + (size_t)NUM_FINE * 128;     // [NUM_COARSE][128] bf16, 3.2 MB

  hipMemsetAsync(d_out, 0, (size_t)out_size * sizeof(float), stream);

  precompute_kernel<<<FINE_BLOCKS + COARSE_BLOCKS, 256, 0, stream>>>(
      h_dk, h_si, h_sk, h_di, W1, b1, Pf, Pc);

  const int eblocks = (E_EDGES + 127) / 128;
  edge_kernel<<<eblocks, 256, 0, stream>>>(Pf, Pc, h_dk, fidx, cidx, W2, b2, out);
}